// Round 5
// baseline (101.750 us; speedup 1.0000x reference)
//
#include <hip/hip_runtime.h>
#include <math.h>

// NLM denoise: x [2,3,512,512] f32, SWS=11 (121 shifts), TWS=5, circular wrap.
// d2 = ||Pc||^2 + ||Ps||^2 - 2<Pc,Ps>; cross-terms via v_dot2_f32_f16 on f16
// pair table; norms via precomputed vertical 5-sum table V (K^2-prescaled).
// w = exp2(-sqrt(K2*d2)); out = clip(sum w*x / sum w, 0, 1)
//
// 512-thread blocks (32,8,2); tz splits the 11 xs shifts (tz=0: xs -5..0,
// tz=1: xs 1..5) for the SAME 4 outputs, partials combined via LDS reduction
// in the dead ldsX region. LDS 67 KB -> 2 blocks/CU = 16 waves/CU (4/SIMD).
//
// Register-allocator discipline (hard-won across 5 container compiles):
//  * min-waves/EU=4 in ANY spelling -> VGPR 64 + 600 MB scratch spill. Never.
//  * launch_bounds(512,2): cap 256. One toolchain stops at 128 (39.4 us,
//    VALUBusy 78%); another shrinks to 76 "for free" by folding the k-loop's
//    prefetched LDS loads back into their uses (legal: no LDS store/barrier in
//    the loop) -> pipeline destroyed, every step stalls on lgkmcnt (54%, 58us).
//  * Fix: opaque `asm volatile("" : "+v"(x))` on each prefetched value, placed
//    AFTER the step's compute and BEFORE the ring commit. RA cannot remat a
//    load through volatile asm, so the prefetch must complete there -> the
//    load/compute overlap survives at ANY register target, on any toolchain.
//    swP ring held as raw unsigned (bit_cast to h2 at use, free); xw ring as
//    3 scalar f32 rings (clean "v" asm operands; drops the dead .w lane).

#define H_IMG 512
#define W_IMG 512
#define MASK  511
#define HWSZ  (H_IMG * W_IMG)
#define TILE  32
#define HALO  7
#define XD    46          // TILE + 2*HALO
#define YSTR  48          // padded col-stride for yf / ldsY2
#define HSTR  44          // col-stride for ldsH (42 cols used)
#define VSTR  44          // col-stride for ldsV (42 cols used)

typedef _Float16 h2 __attribute__((ext_vector_type(2)));
typedef float f32x2 __attribute__((ext_vector_type(2)));

__device__ __forceinline__ float fdot2(h2 a, h2 b, float c) {
#if __has_builtin(__builtin_amdgcn_fdot2)
    return __builtin_amdgcn_fdot2(a, b, c, false);
#else
    return c + (float)a.x * (float)b.x + (float)a.y * (float)b.y;
#endif
}

__device__ __forceinline__ float fast_exp2(float x) {
#if __has_builtin(__builtin_amdgcn_exp2f)
    return __builtin_amdgcn_exp2f(x);
#else
    return __expf(x * 0.6931471805599453f);
#endif
}

#define K2C   0.23126321070979063f    // (log2(e)/3)^2
#define N2K2 -0.46252642141958126f    // -2*K2C

__global__ __launch_bounds__(512, 2)
void nlm_kernel(const float* __restrict__ x, float* __restrict__ out) {
    __shared__ float4   ldsX[XD * XD];        // 33856 B (reused as reduction scratch)
    __shared__ float    ldsYf[XD * YSTR];     //  8832 B (f32 y, 47 cols used)
    __shared__ unsigned ldsY2[XD * YSTR];     //  8832 B (f16 pair (y_c,y_{c+1}))
    __shared__ float    ldsH[XD * HSTR];      //  8096 B (row 5-norms)
    __shared__ float    ldsV[42 * VSTR];      //  7392 B (K2 * vertical 5-sum of H)
                                              //  total 67008 B -> 2 blocks/CU (512 thr)

    const int n  = blockIdx.z;
    const int ti = blockIdx.y * TILE;
    const int tj = blockIdx.x * TILE;
    const int tx = threadIdx.x;            // 0..31
    const int ty = threadIdx.y;            // 0..7
    const int tz = threadIdx.z;            // 0..1 -> xs-range split
    const int tid = tz * 256 + ty * 32 + tx;

    const float* xb = x + (size_t)n * 3 * HWSZ;

    // ---- A: stage x (tile + halo 7), packed float4 ----
    for (int e = tid; e < XD * XD; e += 512) {
        int r = e / XD, c = e - r * XD;
        int gi = (ti + r - HALO) & MASK;
        int gj = (tj + c - HALO) & MASK;
        size_t o = (size_t)gi * W_IMG + gj;
        ldsX[e] = make_float4(xb[o], xb[o + HWSZ], xb[o + 2 * HWSZ], 0.f);
    }
    __syncthreads();

    // ---- B: luminance (f32), 46 rows x 47 cols (col 46 dup, masked later) ----
    for (int e = tid; e < XD * 47; e += 512) {
        int r = e / 47, c = e - r * 47;
        int cs = (c == 46) ? 45 : c;
        float4 v = ldsX[r * XD + cs];
        float rr = fminf(fmaxf(v.x, 0.f), 1.f);
        float gg = fminf(fmaxf(v.y, 0.f), 1.f);
        float bb = fminf(fmaxf(v.z, 0.f), 1.f);
        ldsYf[r * YSTR + c] = 0.299f * rr + 0.587f * gg + 0.114f * bb;
    }
    __syncthreads();

    // ---- C: f16 pair table: entry[r][c] = (y(c), y(c+1)) ----
    for (int e = tid; e < XD * XD; e += 512) {   // 46x46 entries
        int r = e / XD, c = e - r * XD;
        h2 p;
        p.x = (_Float16)ldsYf[r * YSTR + c];
        p.y = (_Float16)ldsYf[r * YSTR + c + 1];
        ldsY2[r * YSTR + c] = __builtin_bit_cast(unsigned, p);
    }
    __syncthreads();

    // ---- D: row-norm H(r,c) = sum_{d=0..4} yh(r,c+d)^2 ----
    for (int e = tid; e < XD * 42; e += 512) {
        int r = e / 42, c = e - r * 42;
        h2 a  = __builtin_bit_cast(h2, ldsY2[r * YSTR + c]);
        h2 b  = __builtin_bit_cast(h2, ldsY2[r * YSTR + c + 2]);
        h2 cc = __builtin_bit_cast(h2, ldsY2[r * YSTR + c + 4]);
        float x0 = (float)a.x, x1 = (float)a.y;
        float x2 = (float)b.x, x3 = (float)b.y;
        float x4 = (float)cc.x;
        ldsH[r * HSTR + c] = x0*x0 + x1*x1 + x2*x2 + x3*x3 + x4*x4;
    }
    __syncthreads();

    // ---- E: V(r,c) = K2 * sum_{t=0..4} H(r+t,c) ----
    for (int e = tid; e < 42 * 42; e += 512) {
        int r = e / 42, c = e - r * 42;
        const float* hp = &ldsH[r * HSTR + c];
        float s = ((hp[0] + hp[HSTR]) + (hp[2*HSTR] + hp[3*HSTR])) + hp[4*HSTR];
        ldsV[r * VSTR + c] = K2C * s;
    }
    __syncthreads();

    const int jl = tx + HALO;          // LDS col of this thread's column
    const int il = ty * 4 + HALO;      // LDS row of first of 4 outputs

    // center patch as f16 pairs + K2-prescaled center norms (from V table)
    h2 cyP[8][3];
    float Vc[4];
    #pragma unroll
    for (int t = 0; t < 8; ++t) {
        int base = (il - 2 + t) * YSTR + (jl - 2);
        cyP[t][0] = __builtin_bit_cast(h2, ldsY2[base]);
        cyP[t][1] = __builtin_bit_cast(h2, ldsY2[base + 2]);
        h2 z = __builtin_bit_cast(h2, ldsY2[base + 4]);
        z.y = (_Float16)0.f;
        cyP[t][2] = z;
    }
    #pragma unroll
    for (int o = 0; o < 4; ++o)
        Vc[o] = ldsV[(il - 2 + o) * VSTR + (jl - 2)];

    f32x2 acc01[4];   // (num0, num1) packed
    float num2[4], den[4];
    #pragma unroll
    for (int o = 0; o < 4; ++o) {
        acc01[o] = (f32x2){0.f, 0.f};
        num2[o] = 0.f; den[o] = 0.f;
    }

    // xs-range split across tz: tz=0 -> -5..0 (6 iters), tz=1 -> 1..5 (5 iters)
    const int xs_lo = tz ? 1 : -5;
    const int xs_hi = tz ? 5 : 0;

    #pragma unroll 1
    for (int xs = xs_lo; xs <= xs_hi; ++xs) {
        const int jc  = jl - xs - 2;   // shifted 5-window base col
        const int xjc = jl - xs;       // shifted x neighbor col (ldsX)

        unsigned swU[8][3];            // shifted-y f16-pair ring (raw u32)
        float  Wr[4];                  // V-table ring
        float  xw0[4], xw1[4], xw2[4]; // x-neighbor rings (r,g,b)

        #pragma unroll
        for (int t = 0; t < 8; ++t) {
            int base = (il - 7 + t) * YSTR + jc;
            swU[t][0] = ldsY2[base];
            swU[t][1] = ldsY2[base + 2];
            swU[t][2] = ldsY2[base + 4];
        }
        #pragma unroll
        for (int t = 0; t < 4; ++t) {
            Wr[t] = ldsV[(il - 7 + t) * VSTR + jc];
            float4 xv = ldsX[(il - 5 + t) * XD + xjc];
            xw0[t] = xv.x; xw1[t] = xv.y; xw2[t] = xv.z;
        }

        float pd2[4];                  // pending d2 (weight tail deferred 1 step)
        float px0, px1, px2;           // snapshot of xw slot overwritten by commit

        #pragma unroll
        for (int k = 0; k <= 10; ++k) {     // ys = 5 - k
            // prefetch next step's ring entries (issue early)
            unsigned nu0, nu1, nu2; float nWv, nx0, nx1, nx2;
            if (k < 10) {
                const int nr = il + k + 1;
                int base = nr * YSTR + jc;
                nu0 = ldsY2[base];
                nu1 = ldsY2[base + 2];
                nu2 = ldsY2[base + 4];
                nWv = ldsV[(il + k - 3) * VSTR + jc];
                float4 xv = ldsX[(il + k - 1) * XD + xjc];
                nx0 = xv.x; nx1 = xv.y; nx2 = xv.z;
            }

            // row-dot cross terms (f16 MACs, f32 accumulate)
            float s[8];
            #pragma unroll
            for (int t = 0; t < 8; ++t) {
                const int m = (t + k) & 7;
                s[t] = fdot2(cyP[t][0], __builtin_bit_cast(h2, swU[m][0]),
                       fdot2(cyP[t][1], __builtin_bit_cast(h2, swU[m][1]),
                       fdot2(cyP[t][2], __builtin_bit_cast(h2, swU[m][2]), 0.f)));
            }

            // sliding 5-row sums of cross terms
            float S0 = ((s[0] + s[1]) + (s[2] + s[3])) + s[4];
            float S1 = S0 - s[0] + s[5];
            float S2 = S1 - s[1] + s[6];
            float S3 = S2 - s[2] + s[7];

            float d2a[4];
            d2a[0] = fmaf(N2K2, S0, Vc[0] + Wr[k & 3]);
            d2a[1] = fmaf(N2K2, S1, Vc[1] + Wr[(k + 1) & 3]);
            d2a[2] = fmaf(N2K2, S2, Vc[2] + Wr[(k + 2) & 3]);
            d2a[3] = fmaf(N2K2, S3, Vc[3] + Wr[(k + 3) & 3]);

            // ---- deferred weight tail for step k-1 ----
            if (k > 0) {
                #pragma unroll
                for (int o = 0; o < 4; ++o) {
                    int sl = (k - 1 + o) & 3;
                    float v0 = (o == 0) ? px0 : xw0[sl];
                    float v1 = (o == 0) ? px1 : xw1[sl];
                    float v2 = (o == 0) ? px2 : xw2[sl];
                    float sd = __builtin_amdgcn_sqrtf(__builtin_fabsf(pd2[o]));
                    float w  = fast_exp2(-sd);
                    f32x2 bw = {w, w};
                    f32x2 xv01 = {v0, v1};
                    acc01[o] = __builtin_elementwise_fma(bw, xv01, acc01[o]);
                    num2[o] = fmaf(w, v2, num2[o]);
                    den[o] += w;
                }
            }

            // stage current step into pending; commit prefetched ring entries.
            #pragma unroll
            for (int o = 0; o < 4; ++o) pd2[o] = d2a[o];
            if (k < 10) {
                // Opaque identity: forces the prefetched loads to materialize
                // HERE (after this step's compute), so RA cannot fold them back
                // into next step's uses and destroy the pipeline.
                asm volatile("" : "+v"(nu0), "+v"(nu1), "+v"(nu2),
                                  "+v"(nWv), "+v"(nx0), "+v"(nx1), "+v"(nx2));
                px0 = xw0[k & 3]; px1 = xw1[k & 3]; px2 = xw2[k & 3];
                swU[k & 7][0] = nu0;
                swU[k & 7][1] = nu1;
                swU[k & 7][2] = nu2;
                Wr[k & 3] = nWv;
                xw0[k & 3] = nx0; xw1[k & 3] = nx1; xw2[k & 3] = nx2;
            }
        }

        // ---- flush tail for k=10 (ring not overwritten at k=10) ----
        #pragma unroll
        for (int o = 0; o < 4; ++o) {
            int sl = (10 + o) & 3;
            float sd = __builtin_amdgcn_sqrtf(__builtin_fabsf(pd2[o]));
            float w  = fast_exp2(-sd);
            f32x2 bw = {w, w};
            f32x2 xv01 = {xw0[sl], xw1[sl]};
            acc01[o] = __builtin_elementwise_fma(bw, xv01, acc01[o]);
            num2[o] = fmaf(w, xw2[sl], num2[o]);
            den[o] += w;
        }
    }

    // ---- combine tz halves via LDS (reuse dead ldsX region) ----
    // Barrier FIRST: tz halves finish at different times and ldsX (xw ring)
    // is still being read until every thread exits the main loop.
    __syncthreads();
    float4* red = (float4*)ldsX;           // 4 planes of 256 float4 = 16384 B
    const int t = ty * 32 + tx;
    if (tz == 1) {
        #pragma unroll
        for (int o = 0; o < 4; ++o)
            red[o * 256 + t] = make_float4(acc01[o].x, acc01[o].y, num2[o], den[o]);
    }
    __syncthreads();

    // ---- epilogue (tz=0 only) ----
    if (tz == 0) {
        float* ob = out + (size_t)n * 3 * HWSZ;
        #pragma unroll
        for (int o = 0; o < 4; ++o) {
            float4 p = red[o * 256 + t];
            float n0 = acc01[o].x + p.x;
            float n1 = acc01[o].y + p.y;
            float n2 = num2[o] + p.z;
            float dn = den[o] + p.w;
            int gi = ti + ty * 4 + o;
            int gj = tj + tx;
            size_t off = (size_t)gi * W_IMG + gj;
            float inv = __builtin_amdgcn_rcpf(dn);
            float v0 = fminf(fmaxf(n0 * inv, 0.f), 1.f);
            float v1 = fminf(fmaxf(n1 * inv, 0.f), 1.f);
            float v2 = fminf(fmaxf(n2 * inv, 0.f), 1.f);
            ob[off]            = v0;
            ob[off + HWSZ]     = v1;
            ob[off + 2 * HWSZ] = v2;
        }
    }
}

extern "C" void kernel_launch(void* const* d_in, const int* in_sizes, int n_in,
                              void* d_out, int out_size, void* d_ws, size_t ws_size,
                              hipStream_t stream) {
    const float* x = (const float*)d_in[0];
    float* out = (float*)d_out;
    dim3 grid(W_IMG / TILE, H_IMG / TILE, 2);   // (16,16,2) = 512 blocks
    dim3 block(32, 8, 2);                       // 512 threads, mc=4, xs-split
    nlm_kernel<<<grid, block, 0, stream>>>(x, out);
}

// Round 6
// 101.195 us; speedup vs baseline: 1.0055x; 1.0055x over previous
//
#include <hip/hip_runtime.h>
#include <math.h>

// NLM denoise: x [2,3,512,512] f32, SWS=11 (121 shifts), TWS=5, circular wrap.
// d2 = ||Pc||^2 + ||Ps||^2 - 2<Pc,Ps>; cross-terms via v_dot2_f32_f16 on f16
// pair table; norms via precomputed vertical 5-sum table V (K^2-prescaled).
// w = exp2(-sqrt(K2*d2)); out = clip(sum w*x / sum w, 0, 1)
//
// 512-thread blocks (32,8,2); tz splits the 11 xs shifts (tz=0: xs -5..0,
// tz=1: xs 1..5) for the SAME 4 outputs, partials combined via LDS reduction
// in the dead ldsX region. LDS 67 KB -> 2 blocks/CU = 16 waves/CU (4/SIMD).
//
// Scheduling discipline (hard-won across 6 container compiles):
//  * min-waves/EU=4 in ANY spelling -> VGPR 64 + 600 MB scratch spill. Never.
//  * launch_bounds(512,2) (cap 256): toolchain A pre-RA-schedules the k-loop
//    prefetch at the top (VGPR 128, VALUBusy 78%, 39.4 us). Toolchain B sinks
//    the 5 ds_reads to their uses (VGPR 76-80, issue->wait adjacent, raw
//    ~120cy LDS latency per step: VALUBusy 61%, 52-58 us). waves_per_eu(2,4)
//    did NOT fix B (still 76) -> it's a scheduler difference, not occupancy.
//  * Value pins (asm "+v") block RA rematerialization of the prefetched loads
//    but NOT load sinking (r5: 80 reg, still 61%).
//  * Therefore: per-k sched_group_barrier template [DS x5][VALU x30] dictates
//    loads-at-top explicitly. Best-effort semantics: undercounts degrade to
//    status quo, not to a spill disaster. Pins kept for the remat half.

#define H_IMG 512
#define W_IMG 512
#define MASK  511
#define HWSZ  (H_IMG * W_IMG)
#define TILE  32
#define HALO  7
#define XD    46          // TILE + 2*HALO
#define YSTR  48          // padded col-stride for yf / ldsY2
#define HSTR  44          // col-stride for ldsH (42 cols used)
#define VSTR  44          // col-stride for ldsV (42 cols used)

typedef _Float16 h2 __attribute__((ext_vector_type(2)));
typedef float f32x2 __attribute__((ext_vector_type(2)));

__device__ __forceinline__ float fdot2(h2 a, h2 b, float c) {
#if __has_builtin(__builtin_amdgcn_fdot2)
    return __builtin_amdgcn_fdot2(a, b, c, false);
#else
    return c + (float)a.x * (float)b.x + (float)a.y * (float)b.y;
#endif
}

__device__ __forceinline__ float fast_exp2(float x) {
#if __has_builtin(__builtin_amdgcn_exp2f)
    return __builtin_amdgcn_exp2f(x);
#else
    return __expf(x * 0.6931471805599453f);
#endif
}

#define K2C   0.23126321070979063f    // (log2(e)/3)^2
#define N2K2 -0.46252642141958126f    // -2*K2C

// LLVM SchedGroupMask bits (per guide/m137): VALU=0x2, DS=0x80, DS_READ=0x100
#define SGB __builtin_amdgcn_sched_group_barrier

__global__ __launch_bounds__(512, 2)
void nlm_kernel(const float* __restrict__ x, float* __restrict__ out) {
    __shared__ float4   ldsX[XD * XD];        // 33856 B (reused as reduction scratch)
    __shared__ float    ldsYf[XD * YSTR];     //  8832 B (f32 y, 47 cols used)
    __shared__ unsigned ldsY2[XD * YSTR];     //  8832 B (f16 pair (y_c,y_{c+1}))
    __shared__ float    ldsH[XD * HSTR];      //  8096 B (row 5-norms)
    __shared__ float    ldsV[42 * VSTR];      //  7392 B (K2 * vertical 5-sum of H)
                                              //  total 67008 B -> 2 blocks/CU (512 thr)

    const int n  = blockIdx.z;
    const int ti = blockIdx.y * TILE;
    const int tj = blockIdx.x * TILE;
    const int tx = threadIdx.x;            // 0..31
    const int ty = threadIdx.y;            // 0..7
    const int tz = threadIdx.z;            // 0..1 -> xs-range split
    const int tid = tz * 256 + ty * 32 + tx;

    const float* xb = x + (size_t)n * 3 * HWSZ;

    // ---- A: stage x (tile + halo 7), packed float4 ----
    for (int e = tid; e < XD * XD; e += 512) {
        int r = e / XD, c = e - r * XD;
        int gi = (ti + r - HALO) & MASK;
        int gj = (tj + c - HALO) & MASK;
        size_t o = (size_t)gi * W_IMG + gj;
        ldsX[e] = make_float4(xb[o], xb[o + HWSZ], xb[o + 2 * HWSZ], 0.f);
    }
    __syncthreads();

    // ---- B: luminance (f32), 46 rows x 47 cols (col 46 dup, masked later) ----
    for (int e = tid; e < XD * 47; e += 512) {
        int r = e / 47, c = e - r * 47;
        int cs = (c == 46) ? 45 : c;
        float4 v = ldsX[r * XD + cs];
        float rr = fminf(fmaxf(v.x, 0.f), 1.f);
        float gg = fminf(fmaxf(v.y, 0.f), 1.f);
        float bb = fminf(fmaxf(v.z, 0.f), 1.f);
        ldsYf[r * YSTR + c] = 0.299f * rr + 0.587f * gg + 0.114f * bb;
    }
    __syncthreads();

    // ---- C: f16 pair table: entry[r][c] = (y(c), y(c+1)) ----
    for (int e = tid; e < XD * XD; e += 512) {   // 46x46 entries
        int r = e / XD, c = e - r * XD;
        h2 p;
        p.x = (_Float16)ldsYf[r * YSTR + c];
        p.y = (_Float16)ldsYf[r * YSTR + c + 1];
        ldsY2[r * YSTR + c] = __builtin_bit_cast(unsigned, p);
    }
    __syncthreads();

    // ---- D: row-norm H(r,c) = sum_{d=0..4} yh(r,c+d)^2 ----
    for (int e = tid; e < XD * 42; e += 512) {
        int r = e / 42, c = e - r * 42;
        h2 a  = __builtin_bit_cast(h2, ldsY2[r * YSTR + c]);
        h2 b  = __builtin_bit_cast(h2, ldsY2[r * YSTR + c + 2]);
        h2 cc = __builtin_bit_cast(h2, ldsY2[r * YSTR + c + 4]);
        float x0 = (float)a.x, x1 = (float)a.y;
        float x2 = (float)b.x, x3 = (float)b.y;
        float x4 = (float)cc.x;
        ldsH[r * HSTR + c] = x0*x0 + x1*x1 + x2*x2 + x3*x3 + x4*x4;
    }
    __syncthreads();

    // ---- E: V(r,c) = K2 * sum_{t=0..4} H(r+t,c) ----
    for (int e = tid; e < 42 * 42; e += 512) {
        int r = e / 42, c = e - r * 42;
        const float* hp = &ldsH[r * HSTR + c];
        float s = ((hp[0] + hp[HSTR]) + (hp[2*HSTR] + hp[3*HSTR])) + hp[4*HSTR];
        ldsV[r * VSTR + c] = K2C * s;
    }
    __syncthreads();

    const int jl = tx + HALO;          // LDS col of this thread's column
    const int il = ty * 4 + HALO;      // LDS row of first of 4 outputs

    // center patch as f16 pairs + K2-prescaled center norms (from V table)
    h2 cyP[8][3];
    float Vc[4];
    #pragma unroll
    for (int t = 0; t < 8; ++t) {
        int base = (il - 2 + t) * YSTR + (jl - 2);
        cyP[t][0] = __builtin_bit_cast(h2, ldsY2[base]);
        cyP[t][1] = __builtin_bit_cast(h2, ldsY2[base + 2]);
        h2 z = __builtin_bit_cast(h2, ldsY2[base + 4]);
        z.y = (_Float16)0.f;
        cyP[t][2] = z;
    }
    #pragma unroll
    for (int o = 0; o < 4; ++o)
        Vc[o] = ldsV[(il - 2 + o) * VSTR + (jl - 2)];

    f32x2 acc01[4];   // (num0, num1) packed
    float num2[4], den[4];
    #pragma unroll
    for (int o = 0; o < 4; ++o) {
        acc01[o] = (f32x2){0.f, 0.f};
        num2[o] = 0.f; den[o] = 0.f;
    }

    // xs-range split across tz: tz=0 -> -5..0 (6 iters), tz=1 -> 1..5 (5 iters)
    const int xs_lo = tz ? 1 : -5;
    const int xs_hi = tz ? 5 : 0;

    #pragma unroll 1
    for (int xs = xs_lo; xs <= xs_hi; ++xs) {
        const int jc  = jl - xs - 2;   // shifted 5-window base col
        const int xjc = jl - xs;       // shifted x neighbor col (ldsX)

        unsigned swU[8][3];            // shifted-y f16-pair ring (raw u32)
        float  Wr[4];                  // V-table ring
        float  xw0[4], xw1[4], xw2[4]; // x-neighbor rings (r,g,b)

        #pragma unroll
        for (int t = 0; t < 8; ++t) {
            int base = (il - 7 + t) * YSTR + jc;
            swU[t][0] = ldsY2[base];
            swU[t][1] = ldsY2[base + 2];
            swU[t][2] = ldsY2[base + 4];
        }
        #pragma unroll
        for (int t = 0; t < 4; ++t) {
            Wr[t] = ldsV[(il - 7 + t) * VSTR + jc];
            float4 xv = ldsX[(il - 5 + t) * XD + xjc];
            xw0[t] = xv.x; xw1[t] = xv.y; xw2[t] = xv.z;
        }

        float pd2[4];                  // pending d2 (weight tail deferred 1 step)
        float px0, px1, px2;           // snapshot of xw slot overwritten by commit

        #pragma unroll
        for (int k = 0; k <= 10; ++k) {     // ys = 5 - k
            // prefetch next step's ring entries (issue early)
            unsigned nu0, nu1, nu2; float nWv, nx0, nx1, nx2;
            if (k < 10) {
                const int nr = il + k + 1;
                int base = nr * YSTR + jc;
                nu0 = ldsY2[base];
                nu1 = ldsY2[base + 2];
                nu2 = ldsY2[base + 4];
                nWv = ldsV[(il + k - 3) * VSTR + jc];
                float4 xv = ldsX[(il + k - 1) * XD + xjc];
                nx0 = xv.x; nx1 = xv.y; nx2 = xv.z;
                // Scheduling template for this k-step: the ~5 DS loads (may
                // merge to 4 via ds_read2) cluster HERE, then >=30 VALU (this
                // step's dots/sums/tail) before the next step's DS cluster.
                // This pins the issue->wait distance to a full step's compute
                // regardless of the toolchain's pre-RA heuristics.
                SGB(0x180, 5, 0);    // DS | DS_READ, 5 insts
                SGB(0x002, 30, 0);   // then VALU, 30 insts
            }

            // row-dot cross terms (f16 MACs, f32 accumulate)
            float s[8];
            #pragma unroll
            for (int t = 0; t < 8; ++t) {
                const int m = (t + k) & 7;
                s[t] = fdot2(cyP[t][0], __builtin_bit_cast(h2, swU[m][0]),
                       fdot2(cyP[t][1], __builtin_bit_cast(h2, swU[m][1]),
                       fdot2(cyP[t][2], __builtin_bit_cast(h2, swU[m][2]), 0.f)));
            }

            // sliding 5-row sums of cross terms
            float S0 = ((s[0] + s[1]) + (s[2] + s[3])) + s[4];
            float S1 = S0 - s[0] + s[5];
            float S2 = S1 - s[1] + s[6];
            float S3 = S2 - s[2] + s[7];

            float d2a[4];
            d2a[0] = fmaf(N2K2, S0, Vc[0] + Wr[k & 3]);
            d2a[1] = fmaf(N2K2, S1, Vc[1] + Wr[(k + 1) & 3]);
            d2a[2] = fmaf(N2K2, S2, Vc[2] + Wr[(k + 2) & 3]);
            d2a[3] = fmaf(N2K2, S3, Vc[3] + Wr[(k + 3) & 3]);

            // ---- deferred weight tail for step k-1 ----
            if (k > 0) {
                #pragma unroll
                for (int o = 0; o < 4; ++o) {
                    int sl = (k - 1 + o) & 3;
                    float v0 = (o == 0) ? px0 : xw0[sl];
                    float v1 = (o == 0) ? px1 : xw1[sl];
                    float v2 = (o == 0) ? px2 : xw2[sl];
                    float sd = __builtin_amdgcn_sqrtf(__builtin_fabsf(pd2[o]));
                    float w  = fast_exp2(-sd);
                    f32x2 bw = {w, w};
                    f32x2 xv01 = {v0, v1};
                    acc01[o] = __builtin_elementwise_fma(bw, xv01, acc01[o]);
                    num2[o] = fmaf(w, v2, num2[o]);
                    den[o] += w;
                }
            }

            // stage current step into pending; commit prefetched ring entries.
            #pragma unroll
            for (int o = 0; o < 4; ++o) pd2[o] = d2a[o];
            if (k < 10) {
                // Opaque identity: forces the prefetched loads to materialize
                // HERE (after this step's compute), so RA cannot fold them back
                // into next step's uses (remat). Issue order is handled by the
                // SGB template above; this handles the regalloc half.
                asm volatile("" : "+v"(nu0), "+v"(nu1), "+v"(nu2),
                                  "+v"(nWv), "+v"(nx0), "+v"(nx1), "+v"(nx2));
                px0 = xw0[k & 3]; px1 = xw1[k & 3]; px2 = xw2[k & 3];
                swU[k & 7][0] = nu0;
                swU[k & 7][1] = nu1;
                swU[k & 7][2] = nu2;
                Wr[k & 3] = nWv;
                xw0[k & 3] = nx0; xw1[k & 3] = nx1; xw2[k & 3] = nx2;
            }
        }

        // ---- flush tail for k=10 (ring not overwritten at k=10) ----
        #pragma unroll
        for (int o = 0; o < 4; ++o) {
            int sl = (10 + o) & 3;
            float sd = __builtin_amdgcn_sqrtf(__builtin_fabsf(pd2[o]));
            float w  = fast_exp2(-sd);
            f32x2 bw = {w, w};
            f32x2 xv01 = {xw0[sl], xw1[sl]};
            acc01[o] = __builtin_elementwise_fma(bw, xv01, acc01[o]);
            num2[o] = fmaf(w, xw2[sl], num2[o]);
            den[o] += w;
        }
    }

    // ---- combine tz halves via LDS (reuse dead ldsX region) ----
    // Barrier FIRST: tz halves finish at different times and ldsX (xw ring)
    // is still being read until every thread exits the main loop.
    __syncthreads();
    float4* red = (float4*)ldsX;           // 4 planes of 256 float4 = 16384 B
    const int t = ty * 32 + tx;
    if (tz == 1) {
        #pragma unroll
        for (int o = 0; o < 4; ++o)
            red[o * 256 + t] = make_float4(acc01[o].x, acc01[o].y, num2[o], den[o]);
    }
    __syncthreads();

    // ---- epilogue (tz=0 only) ----
    if (tz == 0) {
        float* ob = out + (size_t)n * 3 * HWSZ;
        #pragma unroll
        for (int o = 0; o < 4; ++o) {
            float4 p = red[o * 256 + t];
            float n0 = acc01[o].x + p.x;
            float n1 = acc01[o].y + p.y;
            float n2 = num2[o] + p.z;
            float dn = den[o] + p.w;
            int gi = ti + ty * 4 + o;
            int gj = tj + tx;
            size_t off = (size_t)gi * W_IMG + gj;
            float inv = __builtin_amdgcn_rcpf(dn);
            float v0 = fminf(fmaxf(n0 * inv, 0.f), 1.f);
            float v1 = fminf(fmaxf(n1 * inv, 0.f), 1.f);
            float v2 = fminf(fmaxf(n2 * inv, 0.f), 1.f);
            ob[off]            = v0;
            ob[off + HWSZ]     = v1;
            ob[off + 2 * HWSZ] = v2;
        }
    }
}

extern "C" void kernel_launch(void* const* d_in, const int* in_sizes, int n_in,
                              void* d_out, int out_size, void* d_ws, size_t ws_size,
                              hipStream_t stream) {
    const float* x = (const float*)d_in[0];
    float* out = (float*)d_out;
    dim3 grid(W_IMG / TILE, H_IMG / TILE, 2);   // (16,16,2) = 512 blocks
    dim3 block(32, 8, 2);                       // 512 threads, mc=4, xs-split
    nlm_kernel<<<grid, block, 0, stream>>>(x, out);
}

// Round 7
// 99.614 us; speedup vs baseline: 1.0215x; 1.0159x over previous
//
#include <hip/hip_runtime.h>
#include <math.h>

// NLM denoise: x [2,3,512,512] f32, SWS=11 (121 shifts), TWS=5, circular wrap.
// d2 = ||Pc||^2 + ||Ps||^2 - 2<Pc,Ps>; cross-terms via v_dot2_f32_f16 on f16
// pair table; norms via precomputed vertical 5-sum table V (K^2-prescaled).
// w = exp2(-sqrt(K2*d2)); out = clip(sum w*x / sum w, 0, 1)
//
// 768-thread blocks (32,8,3); tz splits the 11 xs shifts 3 ways
// (tz=0: -5..-2, tz=1: -1..2, tz=2: 3..5) for the SAME 4 outputs; partials
// combined via LDS reduction in the dead ldsX region.
// LDS 67 KB -> 2 blocks/CU; 2 x 12 waves = 24 waves/CU = 6 waves/SIMD.
//
// WHY 3-way (history over 7 container compiles):
//  * Container A's scheduler pipelines the k-loop prefetch (VGPR 128,
//    VALUBusy 78%, 39.4 us @ 2-way split). Container B sinks the ds_reads to
//    their uses (VGPR 76-80, raw ~120cy LDS latency per step, VALUBusy 61%,
//    52-58 us). Attempts to force B into A's schedule ALL failed:
//    waves_per_eu(2,4) (r4), value pins (r5), sched_group_barrier (r6) -
//    each left VGPR at 76-80 and VALUBusy at ~61%.
//  * But an 80-reg thread supports 6 waves/SIMD (512/6=85) - B's codegen is
//    priced for occupancy our 2-way config never supplied (2 blocks x 8
//    waves = 4/SIMD). So: supply it. 3-way split = 12 waves/block, 6/SIMD.
//    TLP hides the un-pipelined LDS latency that ILP negotiation couldn't.
//  * launch_bounds(768,2) [2nd arg = min BLOCKS/CU, CUDA semantics in this
//    toolchain: (512,4) gave cap 64 + 600MB spills] -> cap 512/6 ~ 85 >= the
//    proven-no-spill 80. NEVER set a cap below ~80 for this body.

#define H_IMG 512
#define W_IMG 512
#define MASK  511
#define HWSZ  (H_IMG * W_IMG)
#define TILE  32
#define HALO  7
#define XD    46          // TILE + 2*HALO
#define YSTR  48          // padded col-stride for yf / ldsY2
#define HSTR  44          // col-stride for ldsH (42 cols used)
#define VSTR  44          // col-stride for ldsV (42 cols used)
#define NTHR  768

typedef _Float16 h2 __attribute__((ext_vector_type(2)));
typedef float f32x2 __attribute__((ext_vector_type(2)));

__device__ __forceinline__ float fdot2(h2 a, h2 b, float c) {
#if __has_builtin(__builtin_amdgcn_fdot2)
    return __builtin_amdgcn_fdot2(a, b, c, false);
#else
    return c + (float)a.x * (float)b.x + (float)a.y * (float)b.y;
#endif
}

__device__ __forceinline__ float fast_exp2(float x) {
#if __has_builtin(__builtin_amdgcn_exp2f)
    return __builtin_amdgcn_exp2f(x);
#else
    return __expf(x * 0.6931471805599453f);
#endif
}

#define K2C   0.23126321070979063f    // (log2(e)/3)^2
#define N2K2 -0.46252642141958126f    // -2*K2C

__global__ __launch_bounds__(NTHR, 2)
void nlm_kernel(const float* __restrict__ x, float* __restrict__ out) {
    __shared__ float4   ldsX[XD * XD];        // 33856 B (reused as reduction scratch)
    __shared__ float    ldsYf[XD * YSTR];     //  8832 B (f32 y, 47 cols used)
    __shared__ unsigned ldsY2[XD * YSTR];     //  8832 B (f16 pair (y_c,y_{c+1}))
    __shared__ float    ldsH[XD * HSTR];      //  8096 B (row 5-norms)
    __shared__ float    ldsV[42 * VSTR];      //  7392 B (K2 * vertical 5-sum of H)
                                              //  total 67008 B -> 2 blocks/CU

    const int n  = blockIdx.z;
    const int ti = blockIdx.y * TILE;
    const int tj = blockIdx.x * TILE;
    const int tx = threadIdx.x;            // 0..31
    const int ty = threadIdx.y;            // 0..7
    const int tz = threadIdx.z;            // 0..2 -> xs-range split
    const int tid = tz * 256 + ty * 32 + tx;

    const float* xb = x + (size_t)n * 3 * HWSZ;

    // ---- A: stage x (tile + halo 7), packed float4 ----
    for (int e = tid; e < XD * XD; e += NTHR) {
        int r = e / XD, c = e - r * XD;
        int gi = (ti + r - HALO) & MASK;
        int gj = (tj + c - HALO) & MASK;
        size_t o = (size_t)gi * W_IMG + gj;
        ldsX[e] = make_float4(xb[o], xb[o + HWSZ], xb[o + 2 * HWSZ], 0.f);
    }
    __syncthreads();

    // ---- B: luminance (f32), 46 rows x 47 cols (col 46 dup, masked later) ----
    for (int e = tid; e < XD * 47; e += NTHR) {
        int r = e / 47, c = e - r * 47;
        int cs = (c == 46) ? 45 : c;
        float4 v = ldsX[r * XD + cs];
        float rr = fminf(fmaxf(v.x, 0.f), 1.f);
        float gg = fminf(fmaxf(v.y, 0.f), 1.f);
        float bb = fminf(fmaxf(v.z, 0.f), 1.f);
        ldsYf[r * YSTR + c] = 0.299f * rr + 0.587f * gg + 0.114f * bb;
    }
    __syncthreads();

    // ---- C: f16 pair table: entry[r][c] = (y(c), y(c+1)) ----
    for (int e = tid; e < XD * XD; e += NTHR) {   // 46x46 entries
        int r = e / XD, c = e - r * XD;
        h2 p;
        p.x = (_Float16)ldsYf[r * YSTR + c];
        p.y = (_Float16)ldsYf[r * YSTR + c + 1];
        ldsY2[r * YSTR + c] = __builtin_bit_cast(unsigned, p);
    }
    __syncthreads();

    // ---- D: row-norm H(r,c) = sum_{d=0..4} yh(r,c+d)^2 ----
    for (int e = tid; e < XD * 42; e += NTHR) {
        int r = e / 42, c = e - r * 42;
        h2 a  = __builtin_bit_cast(h2, ldsY2[r * YSTR + c]);
        h2 b  = __builtin_bit_cast(h2, ldsY2[r * YSTR + c + 2]);
        h2 cc = __builtin_bit_cast(h2, ldsY2[r * YSTR + c + 4]);
        float x0 = (float)a.x, x1 = (float)a.y;
        float x2 = (float)b.x, x3 = (float)b.y;
        float x4 = (float)cc.x;
        ldsH[r * HSTR + c] = x0*x0 + x1*x1 + x2*x2 + x3*x3 + x4*x4;
    }
    __syncthreads();

    // ---- E: V(r,c) = K2 * sum_{t=0..4} H(r+t,c) ----
    for (int e = tid; e < 42 * 42; e += NTHR) {
        int r = e / 42, c = e - r * 42;
        const float* hp = &ldsH[r * HSTR + c];
        float s = ((hp[0] + hp[HSTR]) + (hp[2*HSTR] + hp[3*HSTR])) + hp[4*HSTR];
        ldsV[r * VSTR + c] = K2C * s;
    }
    __syncthreads();

    const int jl = tx + HALO;          // LDS col of this thread's column
    const int il = ty * 4 + HALO;      // LDS row of first of 4 outputs

    // center patch as f16 pairs + K2-prescaled center norms (from V table)
    h2 cyP[8][3];
    float Vc[4];
    #pragma unroll
    for (int t = 0; t < 8; ++t) {
        int base = (il - 2 + t) * YSTR + (jl - 2);
        cyP[t][0] = __builtin_bit_cast(h2, ldsY2[base]);
        cyP[t][1] = __builtin_bit_cast(h2, ldsY2[base + 2]);
        h2 z = __builtin_bit_cast(h2, ldsY2[base + 4]);
        z.y = (_Float16)0.f;
        cyP[t][2] = z;
    }
    #pragma unroll
    for (int o = 0; o < 4; ++o)
        Vc[o] = ldsV[(il - 2 + o) * VSTR + (jl - 2)];

    f32x2 acc01[4];   // (num0, num1) packed
    float num2[4], den[4];
    #pragma unroll
    for (int o = 0; o < 4; ++o) {
        acc01[o] = (f32x2){0.f, 0.f};
        num2[o] = 0.f; den[o] = 0.f;
    }

    // xs-range split across tz: tz=0 -> -5..-2 (4), tz=1 -> -1..2 (4),
    // tz=2 -> 3..5 (3). Imbalance cost ~3% of main loop.
    const int xs_lo = -5 + tz * 4;
    const int xs_hi = (tz == 2) ? 5 : (xs_lo + 3);

    #pragma unroll 1
    for (int xs = xs_lo; xs <= xs_hi; ++xs) {
        const int jc  = jl - xs - 2;   // shifted 5-window base col
        const int xjc = jl - xs;       // shifted x neighbor col (ldsX)

        unsigned swU[8][3];            // shifted-y f16-pair ring (raw u32)
        float  Wr[4];                  // V-table ring
        float  xw0[4], xw1[4], xw2[4]; // x-neighbor rings (r,g,b)

        #pragma unroll
        for (int t = 0; t < 8; ++t) {
            int base = (il - 7 + t) * YSTR + jc;
            swU[t][0] = ldsY2[base];
            swU[t][1] = ldsY2[base + 2];
            swU[t][2] = ldsY2[base + 4];
        }
        #pragma unroll
        for (int t = 0; t < 4; ++t) {
            Wr[t] = ldsV[(il - 7 + t) * VSTR + jc];
            float4 xv = ldsX[(il - 5 + t) * XD + xjc];
            xw0[t] = xv.x; xw1[t] = xv.y; xw2[t] = xv.z;
        }

        float pd2[4];                  // pending d2 (weight tail deferred 1 step)
        float px0, px1, px2;           // snapshot of xw slot overwritten by commit

        #pragma unroll
        for (int k = 0; k <= 10; ++k) {     // ys = 5 - k
            // prefetch next step's ring entries (issue early)
            unsigned nu0, nu1, nu2; float nWv, nx0, nx1, nx2;
            if (k < 10) {
                const int nr = il + k + 1;
                int base = nr * YSTR + jc;
                nu0 = ldsY2[base];
                nu1 = ldsY2[base + 2];
                nu2 = ldsY2[base + 4];
                nWv = ldsV[(il + k - 3) * VSTR + jc];
                float4 xv = ldsX[(il + k - 1) * XD + xjc];
                nx0 = xv.x; nx1 = xv.y; nx2 = xv.z;
            }

            // row-dot cross terms (f16 MACs, f32 accumulate)
            float s[8];
            #pragma unroll
            for (int t = 0; t < 8; ++t) {
                const int m = (t + k) & 7;
                s[t] = fdot2(cyP[t][0], __builtin_bit_cast(h2, swU[m][0]),
                       fdot2(cyP[t][1], __builtin_bit_cast(h2, swU[m][1]),
                       fdot2(cyP[t][2], __builtin_bit_cast(h2, swU[m][2]), 0.f)));
            }

            // sliding 5-row sums of cross terms
            float S0 = ((s[0] + s[1]) + (s[2] + s[3])) + s[4];
            float S1 = S0 - s[0] + s[5];
            float S2 = S1 - s[1] + s[6];
            float S3 = S2 - s[2] + s[7];

            float d2a[4];
            d2a[0] = fmaf(N2K2, S0, Vc[0] + Wr[k & 3]);
            d2a[1] = fmaf(N2K2, S1, Vc[1] + Wr[(k + 1) & 3]);
            d2a[2] = fmaf(N2K2, S2, Vc[2] + Wr[(k + 2) & 3]);
            d2a[3] = fmaf(N2K2, S3, Vc[3] + Wr[(k + 3) & 3]);

            // ---- deferred weight tail for step k-1 ----
            if (k > 0) {
                #pragma unroll
                for (int o = 0; o < 4; ++o) {
                    int sl = (k - 1 + o) & 3;
                    float v0 = (o == 0) ? px0 : xw0[sl];
                    float v1 = (o == 0) ? px1 : xw1[sl];
                    float v2 = (o == 0) ? px2 : xw2[sl];
                    float sd = __builtin_amdgcn_sqrtf(__builtin_fabsf(pd2[o]));
                    float w  = fast_exp2(-sd);
                    f32x2 bw = {w, w};
                    f32x2 xv01 = {v0, v1};
                    acc01[o] = __builtin_elementwise_fma(bw, xv01, acc01[o]);
                    num2[o] = fmaf(w, v2, num2[o]);
                    den[o] += w;
                }
            }

            // stage current step into pending; commit prefetched ring entries.
            #pragma unroll
            for (int o = 0; o < 4; ++o) pd2[o] = d2a[o];
            if (k < 10) {
                // Opaque identity: blocks RA from folding the prefetched loads
                // back into next step's uses (rematerialization).
                asm volatile("" : "+v"(nu0), "+v"(nu1), "+v"(nu2),
                                  "+v"(nWv), "+v"(nx0), "+v"(nx1), "+v"(nx2));
                px0 = xw0[k & 3]; px1 = xw1[k & 3]; px2 = xw2[k & 3];
                swU[k & 7][0] = nu0;
                swU[k & 7][1] = nu1;
                swU[k & 7][2] = nu2;
                Wr[k & 3] = nWv;
                xw0[k & 3] = nx0; xw1[k & 3] = nx1; xw2[k & 3] = nx2;
            }
        }

        // ---- flush tail for k=10 (ring not overwritten at k=10) ----
        #pragma unroll
        for (int o = 0; o < 4; ++o) {
            int sl = (10 + o) & 3;
            float sd = __builtin_amdgcn_sqrtf(__builtin_fabsf(pd2[o]));
            float w  = fast_exp2(-sd);
            f32x2 bw = {w, w};
            f32x2 xv01 = {xw0[sl], xw1[sl]};
            acc01[o] = __builtin_elementwise_fma(bw, xv01, acc01[o]);
            num2[o] = fmaf(w, xw2[sl], num2[o]);
            den[o] += w;
        }
    }

    // ---- combine tz thirds via LDS (reuse dead ldsX region) ----
    // Barrier FIRST: tz groups finish at different times and ldsX is still
    // being read until every thread exits the main loop.
    __syncthreads();
    float4* red = (float4*)ldsX;     // 2 tz x 4 o x 256 float4 = 32768 B <= 33856
    const int t = ty * 32 + tx;
    if (tz != 0) {
        #pragma unroll
        for (int o = 0; o < 4; ++o)
            red[((tz - 1) * 4 + o) * 256 + t] =
                make_float4(acc01[o].x, acc01[o].y, num2[o], den[o]);
    }
    __syncthreads();

    // ---- epilogue (tz=0 only) ----
    if (tz == 0) {
        float* ob = out + (size_t)n * 3 * HWSZ;
        #pragma unroll
        for (int o = 0; o < 4; ++o) {
            float4 p1 = red[o * 256 + t];
            float4 p2 = red[(4 + o) * 256 + t];
            float n0 = acc01[o].x + p1.x + p2.x;
            float n1 = acc01[o].y + p1.y + p2.y;
            float n2 = num2[o] + p1.z + p2.z;
            float dn = den[o] + p1.w + p2.w;
            int gi = ti + ty * 4 + o;
            int gj = tj + tx;
            size_t off = (size_t)gi * W_IMG + gj;
            float inv = __builtin_amdgcn_rcpf(dn);
            float v0 = fminf(fmaxf(n0 * inv, 0.f), 1.f);
            float v1 = fminf(fmaxf(n1 * inv, 0.f), 1.f);
            float v2 = fminf(fmaxf(n2 * inv, 0.f), 1.f);
            ob[off]            = v0;
            ob[off + HWSZ]     = v1;
            ob[off + 2 * HWSZ] = v2;
        }
    }
}

extern "C" void kernel_launch(void* const* d_in, const int* in_sizes, int n_in,
                              void* d_out, int out_size, void* d_ws, size_t ws_size,
                              hipStream_t stream) {
    const float* x = (const float*)d_in[0];
    float* out = (float*)d_out;
    dim3 grid(W_IMG / TILE, H_IMG / TILE, 2);   // (16,16,2) = 512 blocks
    dim3 block(32, 8, 3);                       // 768 threads, mc=4, 3-way xs-split
    nlm_kernel<<<grid, block, 0, stream>>>(x, out);
}